// Round 4
// baseline (199.896 us; speedup 1.0000x reference)
//
#include <hip/hip_runtime.h>
#include <cstdint>
#include <cstddef>

#define EPS 1e-8f

// Fixed problem instance
#define Bsz 8
#define Nn  5
#define Kk  5
#define Ll  128
#define Ff  768
#define Tt  11                 // 2N+1
#define KL  640                // K*L
#define ROWS_PER_B 2560        // N*Q*L
#define NROWS 20480
#define F4  192                // Ff/4
#define BN  40                 // B*N
#define SUP_ROWS (BN * KL)     // 25600 total support rows

typedef float v2f __attribute__((ext_vector_type(2)));

// ---------------- zerok: zero bnsum+cnt (+loss) ----------------
// bnsum[40][3][768] + cnt[80] = 92,240 floats = 23,060 float4.
__global__ __launch_bounds__(256) void zerok(float4* __restrict__ z,
                                             float* __restrict__ loss_out)
{
    int gid = blockIdx.x * 256 + threadIdx.x;
    if (gid == 0) loss_out[0] = 0.0f;
    if (gid < (BN * 3 * Ff + 2 * BN) / 4) z[gid] = (float4){0.f, 0.f, 0.f, 0.f};
}

// ---------------- Stage 1p: persistent masked sums -> atomic bnsum ----------------
// 256 blocks x 192 threads = EXACTLY 1 block/CU (was 400 blocks = 1.56/CU, 2x
// tail on 144 CUs). Each block owns 100 consecutive support rows (25600/256),
// split into <=2 bn-segments (segment lengths are multiples of 20 -> 8-deep
// batching + 4-deep tail). Lane owns one float4 column. Flush: 12 atomicAdd
// per thread per segment into zeroed bnsum (no part buffer, no stage2 pass).
// Counts are integer-valued floats -> atomic order-independent (exact).
__global__ __launch_bounds__(192) void stage1p(
    const float* __restrict__ sup,      // [B][N][K][L][F]
    const int*   __restrict__ Bm,       // [B][N][K][L] flattened rows
    const int*   __restrict__ Im,
    float* __restrict__ bnsum,          // [BN][3][Ff]  (zeroed)
    float* __restrict__ cnt)            // [BN][2]      (zeroed)
{
    int blk = blockIdx.x;
    int tid = threadIdx.x;

    int row = blk * (SUP_ROWS / 256);                 // 100 rows per block
    const int row_end = row + (SUP_ROWS / 256);

    while (row < row_end) {
        int bn      = row / KL;
        int seg_end = min(row_end, (bn + 1) * KL);
        int len     = seg_end - row;

        const float4* sp = (const float4*)sup + (size_t)row * F4 + tid;
        const int*    bp = Bm + row;                  // uniform -> s_load
        const int*    ip = Im + row;

        v2f tB0 = {0.f,0.f}, tB1 = tB0, tI0 = tB0, tI1 = tB0, tA0 = tB0, tA1 = tB0;
        int cB = 0, cI = 0;

        int r = 0;
        for (; r + 8 <= len; r += 8) {
            float4 v[8];
            #pragma unroll
            for (int j = 0; j < 8; ++j) v[j] = sp[(size_t)(r + j) * F4];
            #pragma unroll
            for (int j = 0; j < 8; ++j) {
                v2f lo = {v[j].x, v[j].y};
                v2f hi = {v[j].z, v[j].w};
                tA0 += lo; tA1 += hi;
                if (bp[r + j]) { tB0 += lo; tB1 += hi; ++cB; }
                if (ip[r + j]) { tI0 += lo; tI1 += hi; ++cI; }
            }
        }
        for (; r + 4 <= len; r += 4) {                // tail (len % 8 == 4 cases)
            float4 v[4];
            #pragma unroll
            for (int j = 0; j < 4; ++j) v[j] = sp[(size_t)(r + j) * F4];
            #pragma unroll
            for (int j = 0; j < 4; ++j) {
                v2f lo = {v[j].x, v[j].y};
                v2f hi = {v[j].z, v[j].w};
                tA0 += lo; tA1 += hi;
                if (bp[r + j]) { tB0 += lo; tB1 += hi; ++cB; }
                if (ip[r + j]) { tI0 += lo; tI1 += hi; ++cI; }
            }
        }

        float* dst = bnsum + (size_t)bn * (3 * Ff) + tid * 4;
        atomicAdd(dst + 0,          tB0.x); atomicAdd(dst + 1,          tB0.y);
        atomicAdd(dst + 2,          tB1.x); atomicAdd(dst + 3,          tB1.y);
        atomicAdd(dst + Ff + 0,     tI0.x); atomicAdd(dst + Ff + 1,     tI0.y);
        atomicAdd(dst + Ff + 2,     tI1.x); atomicAdd(dst + Ff + 3,     tI1.y);
        atomicAdd(dst + 2 * Ff + 0, tA0.x); atomicAdd(dst + 2 * Ff + 1, tA0.y);
        atomicAdd(dst + 2 * Ff + 2, tA1.x); atomicAdd(dst + 2 * Ff + 3, tA1.y);
        if (tid == 0) {
            atomicAdd(&cnt[2 * bn + 0], (float)cB);
            atomicAdd(&cnt[2 * bn + 1], (float)cI);
        }
        row = seg_end;
    }
}

// ---------------- Stage 3: proto build + logits + argmax + NLL ----------------
// 256 blocks x 256 threads = EXACTLY 1 block/CU, 1 wave/SIMD (was 320 blocks,
// 2x tail on 64 CUs). Block = 80 rows; thread = 10 rows x 1/32-fragment ->
// each LDS pv read feeds 40 FMA; LDS traffic 69 MB (was 87). Prologue builds
// scaled prototypes from bnsum/cnt per block (fuses old stage2f; bnsum is
// L2-hot, 32x redundancy per b is cheap). Query loads double-buffered u/w,
// 10 in flight -> 40 KB/CU outstanding >> 9.2 KB needed for HBM saturation.
#define S3_ROWS 80
#define S3_NBLK (NROWS / S3_ROWS)          // 256

__global__ __launch_bounds__(256, 1) void stage3(
    const float* __restrict__ query,    // [B][2560][Ff]
    const float* __restrict__ bnsum,    // [BN][3][Ff]
    const float* __restrict__ cnt,      // [BN][2]
    const int*   __restrict__ label,    // [NROWS]
    float* __restrict__ out_logits,     // [NROWS][Tt]
    float* __restrict__ out_pred,       // [NROWS]
    float* __restrict__ loss_out)       // [1]
{
    __shared__ float4 ldsP[Tt * F4];    // 33,792 B
    __shared__ float  sCnt[2 * Nn];
    __shared__ float  sScale[Tt];
    __shared__ float  lred[4];

    int blk = blockIdx.x;
    int b   = blk >> 5;                 // 32 blocks per b
    int tid = threadIdx.x;

    // Phase A: scales from cnt
    if (tid < 2 * Nn) sCnt[tid] = cnt[2 * Nn * b + tid];
    __syncthreads();
    if (tid < Tt) {
        if (tid == 0) {
            float cO = (float)(KL * Nn);
            #pragma unroll
            for (int k = 0; k < 2 * Nn; ++k) cO -= sCnt[k];
            sScale[0] = 1.0f / (cO + EPS);
        } else {
            sScale[tid] = 1.0f / (sCnt[tid - 1] + EPS);
        }
    }
    __syncthreads();

    // Phase B: scaled prototypes into LDS. t=0 -> O = sum_n(All-B-I).
    const float4* bs = (const float4*)bnsum + (size_t)b * Nn * 3 * F4;
    for (int idx = tid; idx < Tt * F4; idx += 256) {
        int t  = idx / F4;
        int f4 = idx - t * F4;
        float4 val;
        if (t == 0) {
            float sx = 0, sy = 0, sz = 0, sw = 0;
            #pragma unroll
            for (int n = 0; n < Nn; ++n) {
                float4 A  = bs[(n * 3 + 2) * F4 + f4];
                float4 Bv = bs[(n * 3 + 0) * F4 + f4];
                float4 Iv = bs[(n * 3 + 1) * F4 + f4];
                sx += A.x - Bv.x - Iv.x; sy += A.y - Bv.y - Iv.y;
                sz += A.z - Bv.z - Iv.z; sw += A.w - Bv.w - Iv.w;
            }
            val = (float4){sx, sy, sz, sw};
        } else {
            int n  = (t - 1) >> 1;
            int st = (t - 1) & 1;
            val = bs[(n * 3 + st) * F4 + f4];
        }
        float sc = sScale[t];
        val.x *= sc; val.y *= sc; val.z *= sc; val.w *= sc;
        ldsP[idx] = val;
    }
    __syncthreads();

    // Phase C: GEMM. p = row-group (10 rows), s = 1/32 fragment.
    int p = tid >> 5;                   // 0..7
    int s = tid & 31;                   // 0..31

    size_t row0 = (size_t)blk * S3_ROWS + p * 10;
    const float4* qb = (const float4*)query + row0 * F4 + s;

    float a[10][Tt];
    #pragma unroll
    for (int r = 0; r < 10; ++r)
        #pragma unroll
        for (int t = 0; t < Tt; ++t) a[r][t] = 0.0f;

    float4 u[10], w[10];
    #pragma unroll
    for (int r = 0; r < 10; ++r) u[r] = qb[(size_t)r * F4];      // j=0

    const float4* pb = ldsP + s;
    for (int jj = 0; jj < 3; ++jj) {    // rolled: ~7.6 KB body, I-cache safe
        int j0 = 2 * jj, j1 = 2 * jj + 1;
        #pragma unroll
        for (int r = 0; r < 10; ++r) w[r] = qb[(size_t)r * F4 + (j0 + 1) * 32];
        #pragma unroll
        for (int t = 0; t < Tt; ++t) {
            float4 pv = pb[t * F4 + j0 * 32];
            #pragma unroll
            for (int r = 0; r < 10; ++r) {
                float d = a[r][t];
                d = fmaf(u[r].x, pv.x, d); d = fmaf(u[r].y, pv.y, d);
                d = fmaf(u[r].z, pv.z, d); d = fmaf(u[r].w, pv.w, d);
                a[r][t] = d;
            }
        }
        int o2 = (jj < 2) ? (j1 + 1) * 32 : 0;
        #pragma unroll
        for (int r = 0; r < 10; ++r) u[r] = qb[(size_t)r * F4 + o2];
        #pragma unroll
        for (int t = 0; t < Tt; ++t) {
            float4 pv = pb[t * F4 + j1 * 32];
            #pragma unroll
            for (int r = 0; r < 10; ++r) {
                float d = a[r][t];
                d = fmaf(w[r].x, pv.x, d); d = fmaf(w[r].y, pv.y, d);
                d = fmaf(w[r].z, pv.z, d); d = fmaf(w[r].w, pv.w, d);
                a[r][t] = d;
            }
        }
    }

    // reduce across the 32 fragment lanes
    #pragma unroll
    for (int r = 0; r < 10; ++r)
        #pragma unroll
        for (int t = 0; t < Tt; ++t) {
            float v = a[r][t];
            v += __shfl_xor(v, 1, 32);  v += __shfl_xor(v, 2, 32);
            v += __shfl_xor(v, 4, 32);  v += __shfl_xor(v, 8, 32);
            v += __shfl_xor(v, 16, 32);
            a[r][t] = v;
        }

    // epilogue: lane s (<10) handles row row0+s (compile-time select chain)
    float wloss = 0.0f;
    if (s < 10) {
        float rv[Tt];
        #pragma unroll
        for (int t = 0; t < Tt; ++t)
            rv[t] = (s == 0) ? a[0][t] : (s == 1) ? a[1][t] : (s == 2) ? a[2][t]
                  : (s == 3) ? a[3][t] : (s == 4) ? a[4][t] : (s == 5) ? a[5][t]
                  : (s == 6) ? a[6][t] : (s == 7) ? a[7][t] : (s == 8) ? a[8][t]
                  : a[9][t];
        size_t grow = row0 + s;

        float m = rv[0]; int bt = 0;
        #pragma unroll
        for (int t = 1; t < Tt; ++t) if (rv[t] > m) { m = rv[t]; bt = t; }  // first-max
        float sum = 0.0f;
        #pragma unroll
        for (int t = 0; t < Tt; ++t) sum += __expf(rv[t] - m);
        int lab = label[grow];
        float labv = rv[0];
        #pragma unroll
        for (int t = 1; t < Tt; ++t) labv = (lab == t) ? rv[t] : labv;
        #pragma unroll
        for (int t = 0; t < Tt; ++t) out_logits[grow * Tt + t] = rv[t];
        out_pred[grow] = (float)bt;
        wloss = (m + __logf(sum)) - labv;
    }
    // block loss reduce -> one atomic per block
    #pragma unroll
    for (int off = 32; off > 0; off >>= 1) wloss += __shfl_xor(wloss, off, 64);
    if ((tid & 63) == 0) lred[tid >> 6] = wloss;
    __syncthreads();
    if (tid == 0)
        atomicAdd(loss_out, (lred[0] + lred[1] + lred[2] + lred[3]) * (1.0f / (float)NROWS));
}

// ---------------- Host launch ----------------
extern "C" void kernel_launch(void* const* d_in, const int* in_sizes, int n_in,
                              void* d_out, int out_size, void* d_ws, size_t ws_size,
                              hipStream_t stream) {
    const float* sup   = (const float*)d_in[0];
    const float* query = (const float*)d_in[1];
    const int*   Bm    = (const int*)d_in[2];
    const int*   Im    = (const int*)d_in[3];
    const int*   lab   = (const int*)d_in[4];

    // ws layout: bnsum [40][3][768] | cnt [40][2]   (contiguous -> one zerok)
    float* w     = (float*)d_ws;
    float* bnsum = w;
    float* cnt   = bnsum + (size_t)BN * 3 * Ff;            // +92,160

    float* loss_out   = (float*)d_out;
    float* out_logits = (float*)d_out + 1;
    float* out_pred   = (float*)d_out + 1 + (size_t)NROWS * Tt;

    zerok<<<91, 256, 0, stream>>>((float4*)w, loss_out);
    stage1p<<<256, 192, 0, stream>>>(sup, Bm, Im, bnsum, cnt);
    stage3<<<S3_NBLK, 256, 0, stream>>>(query, bnsum, cnt, lab,
                                        out_logits, out_pred, loss_out);
}

// Round 6
// 195.850 us; speedup vs baseline: 1.0207x; 1.0207x over previous
//
#include <hip/hip_runtime.h>
#include <cstdint>
#include <cstddef>

#define EPS 1e-8f

// Fixed problem instance
#define Bsz 8
#define Nn  5
#define Kk  5
#define Ll  128
#define Ff  768
#define Tt  11                 // 2N+1
#define KL  640                // K*L
#define ROWS_PER_B 2560        // N*Q*L
#define NROWS 20480
#define F4  192                // Ff/4
#define BN  40                 // B*N

// ---- stage1 geometry ----
#define S1_ROWS 64
#define S1_G    4                  // row-groups per block
#define S1_GR   16                 // rows per group
#define S1_CH   (KL / S1_ROWS)     // 10 chunks per bn
#define S1_NBLK (BN * S1_CH)       // 400 blocks
#define PART_STRIDE (3 * Ff)       // 2304 floats per record [B|I|All]
#define PART_STRIDE4 (PART_STRIDE / 4)  // 576

typedef float v2f __attribute__((ext_vector_type(2)));

// ---------------- Stage 1: masked partial sums ----------------
// 400 blocks x 768 threads. Block = 64 rows as 4 groups x 16 rows; 192 lanes
// own one float4 column each. Groups combine via LDS tree -> one part record
// per block. Deterministic (no atomics; absmax 0.0625 at R3 vs 0.5 with the
// R4 atomic variant).
__global__ __launch_bounds__(768) void stage1(
    const float* __restrict__ sup,      // [B][N][K][L][F]
    const int*   __restrict__ Bm,       // [B][N][K][L]
    const int*   __restrict__ Im,
    float* __restrict__ part,           // [S1_NBLK][3][Ff]
    float* __restrict__ pcnt)           // [S1_NBLK][2]
{
    __shared__ float4 red[S1_G * 3 * F4];   // 36,864 B
    __shared__ float  redc[S1_G * 2];

    int blk = blockIdx.x;
    int bn  = blk / S1_CH;
    int ch  = blk - bn * S1_CH;
    int tid = threadIdx.x;
    int g   = tid / 192;
    int col = tid - g * 192;
    int rbase = ch * S1_ROWS + g * S1_GR;

    const float4* sp = (const float4*)(sup + ((size_t)bn * KL + rbase) * Ff) + col;
    const int*    bp = Bm + bn * KL + rbase;   // group-uniform
    const int*    ip = Im + bn * KL + rbase;

    v2f tB0 = {0.f,0.f}, tB1 = tB0, tI0 = tB0, tI1 = tB0, tA0 = tB0, tA1 = tB0;
    int cB = 0, cI = 0;

    #pragma unroll
    for (int h = 0; h < S1_GR / 8; ++h) {
        float4 v[8];
        #pragma unroll
        for (int j = 0; j < 8; ++j) v[j] = sp[(size_t)(h * 8 + j) * F4];
        #pragma unroll
        for (int j = 0; j < 8; ++j) {
            int p = h * 8 + j;
            v2f lo = {v[j].x, v[j].y};
            v2f hi = {v[j].z, v[j].w};
            tA0 += lo; tA1 += hi;
            if (bp[p]) { tB0 += lo; tB1 += hi; ++cB; }
            if (ip[p]) { tI0 += lo; tI1 += hi; ++cI; }
        }
    }

    red[(g * 3 + 0) * F4 + col] = (float4){tB0.x, tB0.y, tB1.x, tB1.y};
    red[(g * 3 + 1) * F4 + col] = (float4){tI0.x, tI0.y, tI1.x, tI1.y};
    red[(g * 3 + 2) * F4 + col] = (float4){tA0.x, tA0.y, tA1.x, tA1.y};
    if (col == 0) { redc[g * 2] = (float)cB; redc[g * 2 + 1] = (float)cI; }
    __syncthreads();

    if (tid < 3 * F4) {
        int set = tid / F4;
        int c   = tid - set * F4;
        float4 a = red[(0 * 3 + set) * F4 + c];
        float4 b = red[(1 * 3 + set) * F4 + c];
        float4 d = red[(2 * 3 + set) * F4 + c];
        float4 e = red[(3 * 3 + set) * F4 + c];
        float4 s = {a.x + b.x + d.x + e.x, a.y + b.y + d.y + e.y,
                    a.z + b.z + d.z + e.z, a.w + b.w + d.w + e.w};
        ((float4*)(part + (size_t)blk * PART_STRIDE))[tid] = s;
    }
    if (tid == 0) {
        pcnt[2 * (size_t)blk]     = redc[0] + redc[2] + redc[4] + redc[6];
        pcnt[2 * (size_t)blk + 1] = redc[1] + redc[3] + redc[5] + redc[7];
    }
}

// ---------------- Stage 2 (fused): chunks -> scaled prototypes ----------------
// 32 blocks (b x F-quarter) x 512 threads. Reduces part slice + pcnt into LDS,
// then builds proto[b][t][slice] directly.
#define S2_Q  4
#define S2_QF (F4 / S2_Q)   // 48 float4 per quarter

__global__ __launch_bounds__(512) void stage2f(
    const float* __restrict__ part,     // [S1_NBLK][3][Ff]
    const float* __restrict__ pcnt,     // [S1_NBLK][2]
    float* __restrict__ proto,          // [Bsz][Tt][Ff]
    float* __restrict__ loss_out)
{
    __shared__ float4 bns[Nn * 3 * S2_QF];   // 11,520 B
    __shared__ float  scnt[2 * Nn];

    int blk = blockIdx.x;
    int b   = blk / S2_Q;
    int q   = blk - b * S2_Q;
    int tid = threadIdx.x;

    if (blk == 0 && tid == 0) loss_out[0] = 0.0f;

    for (int it = tid; it < Nn * 3 * S2_QF; it += 512) {   // 720 items
        int n   = it / (3 * S2_QF);
        int r   = it - n * (3 * S2_QF);
        int set = r / S2_QF;
        int f   = r - set * S2_QF;
        const float4* src = (const float4*)part
            + ((size_t)((b * Nn + n) * S1_CH) * 3 + set) * F4 + (q * S2_QF + f);
        float4 s = {0, 0, 0, 0};
        float4 v[S1_CH];
        #pragma unroll
        for (int c = 0; c < S1_CH; ++c) v[c] = src[(size_t)c * PART_STRIDE4];
        #pragma unroll
        for (int c = 0; c < S1_CH; ++c) {
            s.x += v[c].x; s.y += v[c].y; s.z += v[c].z; s.w += v[c].w;
        }
        bns[it] = s;
    }
    if (tid < 2 * Nn) {
        int n = tid >> 1, set = tid & 1;
        float cv = 0.0f;
        #pragma unroll
        for (int c = 0; c < S1_CH; ++c)
            cv += pcnt[2 * ((size_t)(b * Nn + n) * S1_CH + c) + set];
        scnt[tid] = cv;                 // index 2n+set == t-1
    }
    __syncthreads();

    for (int it = tid; it < Tt * S2_QF; it += 512) {       // 528 items
        int t = it / S2_QF;
        int f = it - t * S2_QF;
        float scale;
        float4 val;
        if (t == 0) {
            float cO = (float)(KL * Nn);
            #pragma unroll
            for (int k = 0; k < 2 * Nn; ++k) cO -= scnt[k];
            scale = 1.0f / (cO + EPS);
            float sx = 0, sy = 0, sz = 0, sw = 0;
            #pragma unroll
            for (int n = 0; n < Nn; ++n) {
                float4 A  = bns[(n * 3 + 2) * S2_QF + f];
                float4 Bv = bns[(n * 3 + 0) * S2_QF + f];
                float4 Iv = bns[(n * 3 + 1) * S2_QF + f];
                sx += A.x - Bv.x - Iv.x; sy += A.y - Bv.y - Iv.y;
                sz += A.z - Bv.z - Iv.z; sw += A.w - Bv.w - Iv.w;
            }
            val = (float4){sx, sy, sz, sw};
        } else {
            int n  = (t - 1) >> 1;
            int st = (t - 1) & 1;
            scale = 1.0f / (scnt[t - 1] + EPS);
            val = bns[(n * 3 + st) * S2_QF + f];
        }
        val.x *= scale; val.y *= scale; val.z *= scale; val.w *= scale;
        ((float4*)proto)[((size_t)b * Tt + t) * F4 + q * S2_QF + f] = val;
    }
}

// ---------------- Stage 3: logits + argmax + NLL ----------------
// 320 blocks x 128 threads. Thread = 8 rows x 1/16-fragment: 32 FMA per LDS
// pv read; LDS traffic 87 MB. j-loop rolled (6 iters, 2 j-steps, ~6 KB body,
// I-cache safe); query loads double-buffered u/w. All acc indices
// compile-time. Best-measured stage3 variant (R3 total 195.2 us).
#define S3_ROWS 64
#define S3_NBLK (NROWS / S3_ROWS)          // 320

__global__ __launch_bounds__(128) void stage3(
    const float* __restrict__ query,    // [B][2560][Ff]
    const float* __restrict__ proto,    // [Bsz][Tt][Ff]
    const int*   __restrict__ label,    // [NROWS]
    float* __restrict__ out_logits,     // [NROWS][Tt]
    float* __restrict__ out_pred,       // [NROWS]
    float* __restrict__ loss_out)       // [1]
{
    __shared__ float4 ldsP[Tt * F4];    // 33,792 B
    __shared__ float  lred[2];

    int blk = blockIdx.x;
    int tid = threadIdx.x;
    int b   = blk / (ROWS_PER_B / S3_ROWS);

    const float4* pp = (const float4*)proto + (size_t)b * Tt * F4;
    for (int idx = tid; idx < Tt * F4; idx += 128) ldsP[idx] = pp[idx];
    __syncthreads();

    int p = tid >> 4;                   // row-oct 0..7
    int s = tid & 15;                   // fragment 0..15

    size_t row0 = (size_t)blk * S3_ROWS + p * 8;
    const float4* qb = (const float4*)query + row0 * F4 + s;

    float a[8][Tt];
    #pragma unroll
    for (int r = 0; r < 8; ++r)
        #pragma unroll
        for (int t = 0; t < Tt; ++t) a[r][t] = 0.0f;

    float4 u[8], w[8];
    #pragma unroll
    for (int r = 0; r < 8; ++r) u[r] = qb[r * F4];      // j=0

    const float4* pb = ldsP + s;
    for (int jj = 0; jj < 6; ++jj) {
        int j0 = 2 * jj, j1 = 2 * jj + 1;
        // prefetch j1 while computing j0
        #pragma unroll
        for (int r = 0; r < 8; ++r) w[r] = qb[r * F4 + j1 * 16];
        #pragma unroll
        for (int t = 0; t < Tt; ++t) {
            float4 pv = pb[t * F4 + j0 * 16];
            #pragma unroll
            for (int r = 0; r < 8; ++r) {
                float d = a[r][t];
                d = fmaf(u[r].x, pv.x, d); d = fmaf(u[r].y, pv.y, d);
                d = fmaf(u[r].z, pv.z, d); d = fmaf(u[r].w, pv.w, d);
                a[r][t] = d;
            }
        }
        // prefetch j0 of next iter while computing j1 (clamped on last iter)
        int o2 = (jj < 5) ? (2 * jj + 2) * 16 : 0;
        #pragma unroll
        for (int r = 0; r < 8; ++r) u[r] = qb[r * F4 + o2];
        #pragma unroll
        for (int t = 0; t < Tt; ++t) {
            float4 pv = pb[t * F4 + j1 * 16];
            #pragma unroll
            for (int r = 0; r < 8; ++r) {
                float d = a[r][t];
                d = fmaf(w[r].x, pv.x, d); d = fmaf(w[r].y, pv.y, d);
                d = fmaf(w[r].z, pv.z, d); d = fmaf(w[r].w, pv.w, d);
                a[r][t] = d;
            }
        }
    }

    // reduce across the 16 fragment lanes
    #pragma unroll
    for (int r = 0; r < 8; ++r)
        #pragma unroll
        for (int t = 0; t < Tt; ++t) {
            float v = a[r][t];
            v += __shfl_xor(v, 1, 16); v += __shfl_xor(v, 2, 16);
            v += __shfl_xor(v, 4, 16); v += __shfl_xor(v, 8, 16);
            a[r][t] = v;
        }

    // epilogue: lane s (<8) handles row row0+s (compile-time select chain)
    float wloss = 0.0f;
    if (s < 8) {
        float rv[Tt];
        #pragma unroll
        for (int t = 0; t < Tt; ++t)
            rv[t] = (s == 0) ? a[0][t] : (s == 1) ? a[1][t] : (s == 2) ? a[2][t]
                  : (s == 3) ? a[3][t] : (s == 4) ? a[4][t] : (s == 5) ? a[5][t]
                  : (s == 6) ? a[6][t] : a[7][t];
        size_t grow = row0 + s;

        float m = rv[0]; int bt = 0;
        #pragma unroll
        for (int t = 1; t < Tt; ++t) if (rv[t] > m) { m = rv[t]; bt = t; }  // first-max
        float sum = 0.0f;
        #pragma unroll
        for (int t = 0; t < Tt; ++t) sum += __expf(rv[t] - m);
        int lab = label[grow];
        float labv = rv[0];
        #pragma unroll
        for (int t = 1; t < Tt; ++t) labv = (lab == t) ? rv[t] : labv;
        #pragma unroll
        for (int t = 0; t < Tt; ++t) out_logits[grow * Tt + t] = rv[t];
        out_pred[grow] = (float)bt;
        wloss = (m + __logf(sum)) - labv;
    }
    // block loss reduce -> one atomic per block
    #pragma unroll
    for (int off = 32; off > 0; off >>= 1) wloss += __shfl_xor(wloss, off, 64);
    if ((tid & 63) == 0) lred[tid >> 6] = wloss;
    __syncthreads();
    if (tid == 0)
        atomicAdd(loss_out, (lred[0] + lred[1]) * (1.0f / (float)NROWS));
}

// ---------------- Host launch ----------------
extern "C" void kernel_launch(void* const* d_in, const int* in_sizes, int n_in,
                              void* d_out, int out_size, void* d_ws, size_t ws_size,
                              hipStream_t stream) {
    const float* sup   = (const float*)d_in[0];
    const float* query = (const float*)d_in[1];
    const int*   Bm    = (const int*)d_in[2];
    const int*   Im    = (const int*)d_in[3];
    const int*   lab   = (const int*)d_in[4];

    // ws layout: part [400][2304] | pcnt [400][2] | proto [8][11][768]
    float* w     = (float*)d_ws;
    float* part  = w;
    float* pcnt  = part + (size_t)S1_NBLK * PART_STRIDE;   // +921,600
    float* proto = pcnt + 2 * S1_NBLK;                     // +800 (16B-aligned)

    float* loss_out   = (float*)d_out;
    float* out_logits = (float*)d_out + 1;
    float* out_pred   = (float*)d_out + 1 + (size_t)NROWS * Tt;

    stage1<<<S1_NBLK, 768, 0, stream>>>(sup, Bm, Im, part, pcnt);
    stage2f<<<Bsz * S2_Q, 512, 0, stream>>>(part, pcnt, proto, loss_out);
    stage3<<<S3_NBLK, 128, 0, stream>>>(query, proto, lab,
                                        out_logits, out_pred, loss_out);
}